// Round 15
// baseline (159.670 us; speedup 1.0000x reference)
//
#include <hip/hip_runtime.h>

typedef __attribute__((ext_vector_type(8))) short short8;
typedef __attribute__((ext_vector_type(4))) float f32x4;

#define ROWS 16384   // B*N
#define DIM 64
#define NCODES 8192
#define KT_FB 256
#define CTS_PER_BLOCK 32   // 512 codes per y-block

// ws layout (bytes)
#define WS_BEST   0            // 16384 * 8 = 131072
#define WS_COUNTS 131072       // 8192 * 4  = 32768
#define WS_EMAX   163840       // 256 (one float, padded)
#define WS_ENH    164096       // 8192 * 4  = 32768
#define WS_ESWZ   196864       // 512ct * 2kc * 64l * 16B = 1 MB
#define WS_NEED   1245440

__device__ __forceinline__ unsigned long long pack_score(float s, int idx) {
  unsigned u = __float_as_uint(s);
  u ^= (unsigned)((int)u >> 31) | 0x80000000u;
  return ((unsigned long long)u << 32) | (unsigned)(0xFFFF - idx);
}
__device__ __forceinline__ unsigned short bf16hi(float f) {
  unsigned u = __float_as_uint(f);
  return (unsigned short)((u + 0x7FFFu + ((u >> 16) & 1u)) >> 16);
}

__global__ void vq_enorm(const float* __restrict__ embed, float* __restrict__ enh,
                         unsigned* __restrict__ emax2) {
  int k = blockIdx.x * 256 + threadIdx.x;
  const float4* e4 = (const float4*)(embed + (size_t)k * DIM);
  float a = 0.f, b = 0.f, c = 0.f, d = 0.f;
#pragma unroll
  for (int i = 0; i < DIM / 4; ++i) {
    float4 v = e4[i];
    a = fmaf(v.x, v.x, a); b = fmaf(v.y, v.y, b);
    c = fmaf(v.z, v.z, c); d = fmaf(v.w, v.w, d);
  }
  float n2 = (a + b) + (c + d);          // ||e||^2
  enh[k] = 0.5f * n2;
  atomicMax(emax2, __float_as_uint(n2)); // positive floats: uint order == float order
}

// Pre-swizzle embed hi-bf16 into 16x16x32 MFMA B-fragment order (2-term screen
// needs ONLY eh). frag = ct*2 + kc; lane l: code = ct*16+(l&15), k = kc*32+(l>>4)*8+j.
__global__ void vq_prep_e(const float* __restrict__ embed, short* __restrict__ eswz) {
  int u = blockIdx.x * 256 + threadIdx.x;  // 65536 = 512ct * 2kc * 64l
  int l = u & 63, kc = (u >> 6) & 1, ct = u >> 7;
  int code = ct * 16 + (l & 15);
  int kb = kc * 32 + (l >> 4) * 8;
  const float* er = embed + (size_t)code * DIM + kb;
  short8 h8;
#pragma unroll
  for (int j = 0; j < 8; ++j) h8[j] = (short)bf16hi(er[j]);
  ((short8*)eswz)[u] = h8;
}

#define MFMA16(A, B, C) __builtin_amdgcn_mfma_f32_16x16x32_bf16((A), (B), (C), 0, 0, 0)

// Screen, r15: 2-TERM split screen on the r5/r9-proven structure. Screen score
// = (xh + xl).eh - ||e||^2/2; error <= 2^-8 * ||x_row|| * ||e||_max, bounded at
// RUNTIME (row norm via shfl during A-build, Emax via enorm atomicMax) -> the
// margin is rigorous, not guessed. Per ct: 8 MFMAs (4 chains x 2-deep), 2
// B-loads (half of r9: no el fragments exist at all). FLOAT TOP-2 per lane-slot
// closes the in-lane shadowing hole the larger error opens (a true winner
// screened below a same-lane code is still rescored via the second-best).
// Margin-flagged candidates get exact fp32 rescore; packed u64 atomicMax gives
// bit-exact numpy argmax semantics (max score, then lowest index).
__global__ __launch_bounds__(256, 4) void vq_screen(
    const float* __restrict__ x, const float* __restrict__ embed,
    const short* __restrict__ eswz, const float* __restrict__ enh,
    const float* __restrict__ emax2, unsigned long long* __restrict__ best) {
  const int t = threadIdx.x;
  const int l = t & 63, wid = t >> 6;
  const int cl = l & 15, grp = l >> 4;
  const int row0 = blockIdx.x * 128 + wid * 32;
  const int ct0 = blockIdx.y * CTS_PER_BLOCK;

  // A fragments: x rows -> hi/lo bf16 (x == xh + xl up to 2^-16); row-norm
  // partials accumulated for the runtime error bound.
  short8 ahi[2][2], alo[2][2];
  float xn[2] = {0.f, 0.f};
#pragma unroll
  for (int s = 0; s < 2; ++s) {
    const float4* xr4 = (const float4*)(x + (size_t)(row0 + s * 16 + cl) * DIM);
#pragma unroll
    for (int kc = 0; kc < 2; ++kc) {
      const int q = kc * 8 + grp * 2;
      float4 v0 = xr4[q], v1 = xr4[q + 1];
      float vv[8] = {v0.x, v0.y, v0.z, v0.w, v1.x, v1.y, v1.z, v1.w};
#pragma unroll
      for (int j = 0; j < 8; ++j) {
        unsigned short h = bf16hi(vv[j]);
        float r = vv[j] - __uint_as_float((unsigned)h << 16);
        ahi[s][kc][j] = (short)h;
        alo[s][kc][j] = (short)bf16hi(r);
        xn[s] = fmaf(vv[j], vv[j], xn[s]);
      }
    }
  }
  // full row norm: sum the 4 grp-lanes holding this row (l bits 4-5)
#pragma unroll
  for (int s = 0; s < 2; ++s) {
    xn[s] += __shfl_xor(xn[s], 16);
    xn[s] += __shfl_xor(xn[s], 32);
  }
  const float emax = sqrtf(emax2[0]);  // max_c ||e_c||
  float mrg[2];
#pragma unroll
  for (int s = 0; s < 2; ++s)
    mrg[s] = sqrtf(xn[s]) * emax * (2.2f / 256.0f) + 3e-3f;

  float bsc[2][4], psc[2][4];  // top-1 / top-2 screened scores per lane-slot
  int bidx[2][4], sidx[2][4];
#pragma unroll
  for (int s = 0; s < 2; ++s)
#pragma unroll
    for (int j = 0; j < 4; ++j) {
      bsc[s][j] = -3.4e38f; psc[s][j] = -3.4e38f;
      bidx[s][j] = 0; sidx[s][j] = 0;
    }

  const short8* eb = (const short8*)eswz + (size_t)ct0 * 2 * 64;

#pragma unroll 2
  for (int ci = 0; ci < CTS_PER_BLOCK; ++ci) {
    const short8* bt = eb + (size_t)ci * 128;
    short8 bh0 = bt[l], bh1 = bt[64 + l];
    const float eh = enh[(ct0 + ci) * 16 + cl];

    f32x4 a00 = {-eh, -eh, -eh, -eh};  // slot0 k0 (carries bias)
    f32x4 a10 = a00;                   // slot1 k0
    f32x4 a01 = {0.f, 0.f, 0.f, 0.f};  // slot0 k1
    f32x4 a11 = a01;                   // slot1 k1
    // 8 MFMAs, 4 independent 2-deep chains, round-robin
    a00 = MFMA16(ahi[0][0], bh0, a00);
    a10 = MFMA16(ahi[1][0], bh0, a10);
    a01 = MFMA16(ahi[0][1], bh1, a01);
    a11 = MFMA16(ahi[1][1], bh1, a11);
    a00 = MFMA16(alo[0][0], bh0, a00);
    a10 = MFMA16(alo[1][0], bh0, a10);
    a01 = MFMA16(alo[0][1], bh1, a01);
    a11 = MFMA16(alo[1][1], bh1, a11);

    f32x4 s0 = a00 + a01, s1 = a10 + a11;
    const int code = (ct0 + ci) * 16 + cl;
#pragma unroll
    for (int j = 0; j < 4; ++j) {
      float v0 = s0[j], v1 = s1[j];
      if (v0 > bsc[0][j]) {
        psc[0][j] = bsc[0][j]; sidx[0][j] = bidx[0][j];
        bsc[0][j] = v0; bidx[0][j] = code;
      } else if (v0 > psc[0][j]) { psc[0][j] = v0; sidx[0][j] = code; }
      if (v1 > bsc[1][j]) {
        psc[1][j] = bsc[1][j]; sidx[1][j] = bidx[1][j];
        bsc[1][j] = v1; bidx[1][j] = code;
      } else if (v1 > psc[1][j]) { psc[1][j] = v1; sidx[1][j] = code; }
    }
  }

  // Row max over the 16 lanes of each group; flag top-1/top-2 within margin.
  unsigned fmask = 0;  // bits 0..7: top-1, bits 8..15: top-2
#pragma unroll
  for (int s = 0; s < 2; ++s)
#pragma unroll
    for (int j = 0; j < 4; ++j) {
      float m = bsc[s][j];
      m = fmaxf(m, __shfl_xor(m, 1));
      m = fmaxf(m, __shfl_xor(m, 2));
      m = fmaxf(m, __shfl_xor(m, 4));
      m = fmaxf(m, __shfl_xor(m, 8));
      m -= mrg[s];
      if (bsc[s][j] >= m) fmask |= 1u << (s * 4 + j);
      if (psc[s][j] >= m) fmask |= 1u << (s * 4 + j + 8);
    }

  // Exact fp32 rescore of flagged candidates; packed u64 per slot.
  unsigned long long exactp[2][4];
#pragma unroll
  for (int s = 0; s < 2; ++s)
#pragma unroll
    for (int j = 0; j < 4; ++j) exactp[s][j] = 0ull;  // packed -inf

  while (__any((int)(fmask != 0))) {
    const bool act = fmask != 0;
    const int sel = act ? __ffs(fmask) - 1 : 0;
    const int slot = sel & 7, which = sel >> 3;
    int code = 0;
#pragma unroll
    for (int s = 0; s < 2; ++s)
#pragma unroll
      for (int j = 0; j < 4; ++j)
        if (slot == s * 4 + j) code = which ? sidx[s][j] : bidx[s][j];
    int row = act ? (row0 + (slot >> 2) * 16 + grp * 4 + (slot & 3)) : row0;
    if (!act) code = 0;
    const float4* xr = (const float4*)(x + (size_t)row * DIM);
    const float4* er = (const float4*)(embed + (size_t)code * DIM);
    float a0 = 0, a1 = 0, a2 = 0, a3 = 0, n0 = 0, n1 = 0, n2 = 0, n3 = 0;
#pragma unroll
    for (int i = 0; i < 16; ++i) {
      float4 xv = xr[i], ev = er[i];
      a0 = fmaf(xv.x, ev.x, a0); a1 = fmaf(xv.y, ev.y, a1);
      a2 = fmaf(xv.z, ev.z, a2); a3 = fmaf(xv.w, ev.w, a3);
      n0 = fmaf(ev.x, ev.x, n0); n1 = fmaf(ev.y, ev.y, n1);
      n2 = fmaf(ev.z, ev.z, n2); n3 = fmaf(ev.w, ev.w, n3);
    }
    float ex = ((a0 + a1) + (a2 + a3)) - 0.5f * ((n0 + n1) + (n2 + n3));
    unsigned long long cand = act ? pack_score(ex, code) : 0ull;
#pragma unroll
    for (int s = 0; s < 2; ++s)
#pragma unroll
      for (int j = 0; j < 4; ++j)
        if (slot == s * 4 + j) exactp[s][j] = exactp[s][j] > cand ? exactp[s][j] : cand;
    fmask = act ? (fmask & (fmask - 1)) : 0u;
  }

  // (exact score, lowest-idx) reduce across the 16-lane group; atomicMax combine.
#pragma unroll
  for (int s = 0; s < 2; ++s)
#pragma unroll
    for (int j = 0; j < 4; ++j) {
      unsigned long long pk = exactp[s][j], o;
      o = __shfl_xor(pk, 1); pk = pk > o ? pk : o;
      o = __shfl_xor(pk, 2); pk = pk > o ? pk : o;
      o = __shfl_xor(pk, 4); pk = pk > o ? pk : o;
      o = __shfl_xor(pk, 8); pk = pk > o ? pk : o;
      if (cl == 0) atomicMax(&best[row0 + s * 16 + grp * 4 + j], pk);
    }
}

// Fallback (proven round-1 path) if ws is too small for the MFMA screen.
__global__ __launch_bounds__(256, 2) void vq_score_fb(
    const float* __restrict__ x, const float* __restrict__ embed,
    const float* __restrict__ enh, unsigned long long* __restrict__ best) {
  const int row = blockIdx.x * 256 + threadIdx.x;
  const int c0 = blockIdx.y * KT_FB;
  float4 xa[16];
  const float4* xg = (const float4*)(x + (size_t)row * DIM);
#pragma unroll
  for (int i = 0; i < 16; ++i) xa[i] = xg[i];
  float bs = -3.4e38f;
  int bc = 0;
#pragma unroll 2
  for (int c = c0; c < c0 + KT_FB; ++c) {
    const float4* e4 = (const float4*)(embed + (size_t)c * DIM);
    float a0 = 0.f, a1 = 0.f, a2 = 0.f, a3 = 0.f;
#pragma unroll
    for (int i = 0; i < 16; ++i) {
      float4 ev = e4[i];
      a0 = fmaf(xa[i].x, ev.x, a0); a1 = fmaf(xa[i].y, ev.y, a1);
      a2 = fmaf(xa[i].z, ev.z, a2); a3 = fmaf(xa[i].w, ev.w, a3);
    }
    float s = ((a0 + a1) + (a2 + a3)) - enh[c];
    if (s > bs) { bs = s; bc = c; }
  }
  atomicMax(&best[row], pack_score(bs, bc));
}

__global__ void vq_finalize(const unsigned long long* __restrict__ best,
                            const float* __restrict__ embed,
                            const float* __restrict__ node_mask,
                            float* __restrict__ quant,
                            float* __restrict__ out_idx,
                            float* __restrict__ counts) {
  int gid = blockIdx.x * 256 + threadIdx.x;
  int row = gid >> 6, d = gid & 63;
  unsigned long long p = best[row];
  int idx = 0xFFFF - (int)(p & 0xFFFFull);
  quant[gid] = embed[(size_t)idx * DIM + d];
  if (d == 0) {
    out_idx[row] = (float)idx;
    atomicAdd(&counts[idx], node_mask[row]);
  }
}

__global__ void vq_perplexity(const float* __restrict__ counts, float* __restrict__ out) {
  int tid = threadIdx.x;
  float acc = 0.f;
  for (int k = tid; k < NCODES; k += 256) {
    float p = counts[k] * (1.0f / (float)ROWS);
    acc += p * logf(p + 1e-10f);
  }
#pragma unroll
  for (int off = 32; off > 0; off >>= 1) acc += __shfl_down(acc, off);
  __shared__ float red[4];
  if ((tid & 63) == 0) red[tid >> 6] = acc;
  __syncthreads();
  if (tid == 0) out[0] = expf(-((red[0] + red[1]) + (red[2] + red[3])));
}

extern "C" void kernel_launch(void* const* d_in, const int* in_sizes, int n_in,
                              void* d_out, int out_size, void* d_ws, size_t ws_size,
                              hipStream_t stream) {
  const float* x = (const float*)d_in[0];
  const float* node_mask = (const float*)d_in[1];
  const float* embed = (const float*)d_in[2];

  float* out = (float*)d_out;
  float* quant = out;
  float* out_idx = out + (size_t)ROWS * DIM;
  float* out_ppl = out_idx + ROWS;

  unsigned long long* best = (unsigned long long*)((char*)d_ws + WS_BEST);
  float* counts = (float*)((char*)d_ws + WS_COUNTS);
  unsigned* emax2 = (unsigned*)((char*)d_ws + WS_EMAX);
  float* enh = (float*)((char*)d_ws + WS_ENH);
  short* eswz = (short*)((char*)d_ws + WS_ESWZ);

  hipMemsetAsync(d_ws, 0, WS_ENH, stream);  // best + counts + emax2
  vq_enorm<<<NCODES / 256, 256, 0, stream>>>(embed, enh, emax2);
  if (ws_size >= WS_NEED) {
    vq_prep_e<<<256, 256, 0, stream>>>(embed, eswz);
    vq_screen<<<dim3(ROWS / 128, NCODES / (CTS_PER_BLOCK * 16)), 256, 0, stream>>>(
        x, embed, eswz, enh, (const float*)emax2, best);
  } else {
    vq_score_fb<<<dim3(ROWS / 256, NCODES / KT_FB), 256, 0, stream>>>(x, embed, enh, best);
  }
  vq_finalize<<<ROWS * DIM / 256, 256, 0, stream>>>(best, embed, node_mask, quant, out_idx, counts);
  vq_perplexity<<<1, 256, 0, stream>>>(counts, out_ppl);
}

// Round 16
// 130.775 us; speedup vs baseline: 1.2210x; 1.2210x over previous
//
#include <hip/hip_runtime.h>

typedef __attribute__((ext_vector_type(8))) short short8;
typedef __attribute__((ext_vector_type(4))) float f32x4;

#define ROWS 16384   // B*N
#define DIM 64
#define NCODES 8192
#define KT_FB 256
#define CTS_PER_BLOCK 32   // 512 codes per y-block

// ws layout (bytes)
#define WS_BEST   0            // 16384 * 8 = 131072
#define WS_COUNTS 131072       // 8192 * 4  = 32768
#define WS_EMAX   163840       // 256 (one float, padded)
#define WS_ENH    164096       // 8192 * 4  = 32768
#define WS_ESWZ   196864       // 512ct * 2kc * 64l * 16B = 1 MB
#define WS_NEED   1245440

__device__ __forceinline__ unsigned long long pack_score(float s, int idx) {
  unsigned u = __float_as_uint(s);
  u ^= (unsigned)((int)u >> 31) | 0x80000000u;
  return ((unsigned long long)u << 32) | (unsigned)(0xFFFF - idx);
}
__device__ __forceinline__ unsigned short bf16hi(float f) {
  unsigned u = __float_as_uint(f);
  return (unsigned short)((u + 0x7FFFu + ((u >> 16) & 1u)) >> 16);
}

__global__ void vq_enorm(const float* __restrict__ embed, float* __restrict__ enh,
                         unsigned* __restrict__ emax2) {
  int k = blockIdx.x * 256 + threadIdx.x;
  const float4* e4 = (const float4*)(embed + (size_t)k * DIM);
  float a = 0.f, b = 0.f, c = 0.f, d = 0.f;
#pragma unroll
  for (int i = 0; i < DIM / 4; ++i) {
    float4 v = e4[i];
    a = fmaf(v.x, v.x, a); b = fmaf(v.y, v.y, b);
    c = fmaf(v.z, v.z, c); d = fmaf(v.w, v.w, d);
  }
  float n2 = (a + b) + (c + d);          // ||e||^2
  enh[k] = 0.5f * n2;
  atomicMax(emax2, __float_as_uint(n2)); // positive floats: uint order == float order
}

// Pre-swizzle embed hi-bf16 into 16x16x32 MFMA B-fragment order (1-term screen
// needs ONLY eh). frag = ct*2 + kc; lane l: code = ct*16+(l&15), k = kc*32+(l>>4)*8+j.
__global__ void vq_prep_e(const float* __restrict__ embed, short* __restrict__ eswz) {
  int u = blockIdx.x * 256 + threadIdx.x;  // 65536 = 512ct * 2kc * 64l
  int l = u & 63, kc = (u >> 6) & 1, ct = u >> 7;
  int code = ct * 16 + (l & 15);
  int kb = kc * 32 + (l >> 4) * 8;
  const float* er = embed + (size_t)code * DIM + kb;
  short8 h8;
#pragma unroll
  for (int j = 0; j < 8; ++j) h8[j] = (short)bf16hi(er[j]);
  ((short8*)eswz)[u] = h8;
}

#define MFMA16(A, B, C) __builtin_amdgcn_mfma_f32_16x16x32_bf16((A), (B), (C), 0, 0, 0)

// Screen, r16: SINGLE-term screen xh.eh - ||e||^2/2. r15's post-mortem: VALU is
// the dominant pipe (38% vs MFMA 22%); the right work cut shrinks MFMA count
// AND register pressure while keeping VALU flat. vs r15: alo[] deleted
// (-16 VGPR, clears r15's mild spill), 4 MFMAs/ct as 4 independent 1-deep
// chains (zero chain latency), 2 B-loads/ct. Error |x.e - xh.eh| <=
// 2^-8 ||x_row|| ||e||_max (Cauchy-Schwarz, half-ulp bf16 each side), covered
// 2x by r15's VALIDATED runtime margin (2.2/256)*||x||*Emax + 3e-3. Top-2 per
// lane-slot closes the in-lane shadowing hole (two same-slot impostors needed
// to fail). Margin-flagged candidates -> exact fp32 rescore; packed u64
// atomicMax = bit-exact numpy argmax (max score, then lowest index).
__global__ __launch_bounds__(256, 4) void vq_screen(
    const float* __restrict__ x, const float* __restrict__ embed,
    const short* __restrict__ eswz, const float* __restrict__ enh,
    const float* __restrict__ emax2, unsigned long long* __restrict__ best) {
  const int t = threadIdx.x;
  const int l = t & 63, wid = t >> 6;
  const int cl = l & 15, grp = l >> 4;
  const int row0 = blockIdx.x * 128 + wid * 32;
  const int ct0 = blockIdx.y * CTS_PER_BLOCK;

  // A fragments: x rows -> hi bf16 only; row-norm partials for the error bound.
  short8 ahi[2][2];
  float xn[2] = {0.f, 0.f};
#pragma unroll
  for (int s = 0; s < 2; ++s) {
    const float4* xr4 = (const float4*)(x + (size_t)(row0 + s * 16 + cl) * DIM);
#pragma unroll
    for (int kc = 0; kc < 2; ++kc) {
      const int q = kc * 8 + grp * 2;
      float4 v0 = xr4[q], v1 = xr4[q + 1];
      float vv[8] = {v0.x, v0.y, v0.z, v0.w, v1.x, v1.y, v1.z, v1.w};
#pragma unroll
      for (int j = 0; j < 8; ++j) {
        ahi[s][kc][j] = (short)bf16hi(vv[j]);
        xn[s] = fmaf(vv[j], vv[j], xn[s]);
      }
    }
  }
  // full row norm: sum the 4 grp-lanes holding this row (l bits 4-5)
#pragma unroll
  for (int s = 0; s < 2; ++s) {
    xn[s] += __shfl_xor(xn[s], 16);
    xn[s] += __shfl_xor(xn[s], 32);
  }
  const float emax = sqrtf(emax2[0]);  // max_c ||e_c||
  float mrg[2];
#pragma unroll
  for (int s = 0; s < 2; ++s)
    mrg[s] = sqrtf(xn[s]) * emax * (2.2f / 256.0f) + 3e-3f;

  float bsc[2][4], psc[2][4];  // top-1 / top-2 screened scores per lane-slot
  int bidx[2][4], sidx[2][4];
#pragma unroll
  for (int s = 0; s < 2; ++s)
#pragma unroll
    for (int j = 0; j < 4; ++j) {
      bsc[s][j] = -3.4e38f; psc[s][j] = -3.4e38f;
      bidx[s][j] = 0; sidx[s][j] = 0;
    }

  const short8* eb = (const short8*)eswz + (size_t)ct0 * 2 * 64;

#pragma unroll 2
  for (int ci = 0; ci < CTS_PER_BLOCK; ++ci) {
    const short8* bt = eb + (size_t)ci * 128;
    short8 bh0 = bt[l], bh1 = bt[64 + l];
    const float eh = enh[(ct0 + ci) * 16 + cl];

    f32x4 a00 = {-eh, -eh, -eh, -eh};  // slot0 k0 (carries bias)
    f32x4 a10 = a00;                   // slot1 k0
    f32x4 a01 = {0.f, 0.f, 0.f, 0.f};  // slot0 k1
    f32x4 a11 = a01;                   // slot1 k1
    // 4 MFMAs, 4 independent 1-deep chains
    a00 = MFMA16(ahi[0][0], bh0, a00);
    a10 = MFMA16(ahi[1][0], bh0, a10);
    a01 = MFMA16(ahi[0][1], bh1, a01);
    a11 = MFMA16(ahi[1][1], bh1, a11);

    f32x4 s0 = a00 + a01, s1 = a10 + a11;
    const int code = (ct0 + ci) * 16 + cl;
#pragma unroll
    for (int j = 0; j < 4; ++j) {
      float v0 = s0[j], v1 = s1[j];
      if (v0 > bsc[0][j]) {
        psc[0][j] = bsc[0][j]; sidx[0][j] = bidx[0][j];
        bsc[0][j] = v0; bidx[0][j] = code;
      } else if (v0 > psc[0][j]) { psc[0][j] = v0; sidx[0][j] = code; }
      if (v1 > bsc[1][j]) {
        psc[1][j] = bsc[1][j]; sidx[1][j] = bidx[1][j];
        bsc[1][j] = v1; bidx[1][j] = code;
      } else if (v1 > psc[1][j]) { psc[1][j] = v1; sidx[1][j] = code; }
    }
  }

  // Row max over the 16 lanes of each group; flag top-1/top-2 within margin.
  unsigned fmask = 0;  // bits 0..7: top-1, bits 8..15: top-2
#pragma unroll
  for (int s = 0; s < 2; ++s)
#pragma unroll
    for (int j = 0; j < 4; ++j) {
      float m = bsc[s][j];
      m = fmaxf(m, __shfl_xor(m, 1));
      m = fmaxf(m, __shfl_xor(m, 2));
      m = fmaxf(m, __shfl_xor(m, 4));
      m = fmaxf(m, __shfl_xor(m, 8));
      m -= mrg[s];
      if (bsc[s][j] >= m) fmask |= 1u << (s * 4 + j);
      if (psc[s][j] >= m) fmask |= 1u << (s * 4 + j + 8);
    }

  // Exact fp32 rescore of flagged candidates; packed u64 per slot.
  unsigned long long exactp[2][4];
#pragma unroll
  for (int s = 0; s < 2; ++s)
#pragma unroll
    for (int j = 0; j < 4; ++j) exactp[s][j] = 0ull;  // packed -inf

  while (__any((int)(fmask != 0))) {
    const bool act = fmask != 0;
    const int sel = act ? __ffs(fmask) - 1 : 0;
    const int slot = sel & 7, which = sel >> 3;
    int code = 0;
#pragma unroll
    for (int s = 0; s < 2; ++s)
#pragma unroll
      for (int j = 0; j < 4; ++j)
        if (slot == s * 4 + j) code = which ? sidx[s][j] : bidx[s][j];
    int row = act ? (row0 + (slot >> 2) * 16 + grp * 4 + (slot & 3)) : row0;
    if (!act) code = 0;
    const float4* xr = (const float4*)(x + (size_t)row * DIM);
    const float4* er = (const float4*)(embed + (size_t)code * DIM);
    float a0 = 0, a1 = 0, a2 = 0, a3 = 0, n0 = 0, n1 = 0, n2 = 0, n3 = 0;
#pragma unroll
    for (int i = 0; i < 16; ++i) {
      float4 xv = xr[i], ev = er[i];
      a0 = fmaf(xv.x, ev.x, a0); a1 = fmaf(xv.y, ev.y, a1);
      a2 = fmaf(xv.z, ev.z, a2); a3 = fmaf(xv.w, ev.w, a3);
      n0 = fmaf(ev.x, ev.x, n0); n1 = fmaf(ev.y, ev.y, n1);
      n2 = fmaf(ev.z, ev.z, n2); n3 = fmaf(ev.w, ev.w, n3);
    }
    float ex = ((a0 + a1) + (a2 + a3)) - 0.5f * ((n0 + n1) + (n2 + n3));
    unsigned long long cand = act ? pack_score(ex, code) : 0ull;
#pragma unroll
    for (int s = 0; s < 2; ++s)
#pragma unroll
      for (int j = 0; j < 4; ++j)
        if (slot == s * 4 + j) exactp[s][j] = exactp[s][j] > cand ? exactp[s][j] : cand;
    fmask = act ? (fmask & (fmask - 1)) : 0u;
  }

  // (exact score, lowest-idx) reduce across the 16-lane group; atomicMax combine.
#pragma unroll
  for (int s = 0; s < 2; ++s)
#pragma unroll
    for (int j = 0; j < 4; ++j) {
      unsigned long long pk = exactp[s][j], o;
      o = __shfl_xor(pk, 1); pk = pk > o ? pk : o;
      o = __shfl_xor(pk, 2); pk = pk > o ? pk : o;
      o = __shfl_xor(pk, 4); pk = pk > o ? pk : o;
      o = __shfl_xor(pk, 8); pk = pk > o ? pk : o;
      if (cl == 0) atomicMax(&best[row0 + s * 16 + grp * 4 + j], pk);
    }
}

// Fallback (proven round-1 path) if ws is too small for the MFMA screen.
__global__ __launch_bounds__(256, 2) void vq_score_fb(
    const float* __restrict__ x, const float* __restrict__ embed,
    const float* __restrict__ enh, unsigned long long* __restrict__ best) {
  const int row = blockIdx.x * 256 + threadIdx.x;
  const int c0 = blockIdx.y * KT_FB;
  float4 xa[16];
  const float4* xg = (const float4*)(x + (size_t)row * DIM);
#pragma unroll
  for (int i = 0; i < 16; ++i) xa[i] = xg[i];
  float bs = -3.4e38f;
  int bc = 0;
#pragma unroll 2
  for (int c = c0; c < c0 + KT_FB; ++c) {
    const float4* e4 = (const float4*)(embed + (size_t)c * DIM);
    float a0 = 0.f, a1 = 0.f, a2 = 0.f, a3 = 0.f;
#pragma unroll
    for (int i = 0; i < 16; ++i) {
      float4 ev = e4[i];
      a0 = fmaf(xa[i].x, ev.x, a0); a1 = fmaf(xa[i].y, ev.y, a1);
      a2 = fmaf(xa[i].z, ev.z, a2); a3 = fmaf(xa[i].w, ev.w, a3);
    }
    float s = ((a0 + a1) + (a2 + a3)) - enh[c];
    if (s > bs) { bs = s; bc = c; }
  }
  atomicMax(&best[row], pack_score(bs, bc));
}

__global__ void vq_finalize(const unsigned long long* __restrict__ best,
                            const float* __restrict__ embed,
                            const float* __restrict__ node_mask,
                            float* __restrict__ quant,
                            float* __restrict__ out_idx,
                            float* __restrict__ counts) {
  int gid = blockIdx.x * 256 + threadIdx.x;
  int row = gid >> 6, d = gid & 63;
  unsigned long long p = best[row];
  int idx = 0xFFFF - (int)(p & 0xFFFFull);
  quant[gid] = embed[(size_t)idx * DIM + d];
  if (d == 0) {
    out_idx[row] = (float)idx;
    atomicAdd(&counts[idx], node_mask[row]);
  }
}

__global__ void vq_perplexity(const float* __restrict__ counts, float* __restrict__ out) {
  int tid = threadIdx.x;
  float acc = 0.f;
  for (int k = tid; k < NCODES; k += 256) {
    float p = counts[k] * (1.0f / (float)ROWS);
    acc += p * logf(p + 1e-10f);
  }
#pragma unroll
  for (int off = 32; off > 0; off >>= 1) acc += __shfl_down(acc, off);
  __shared__ float red[4];
  if ((tid & 63) == 0) red[tid >> 6] = acc;
  __syncthreads();
  if (tid == 0) out[0] = expf(-((red[0] + red[1]) + (red[2] + red[3])));
}

extern "C" void kernel_launch(void* const* d_in, const int* in_sizes, int n_in,
                              void* d_out, int out_size, void* d_ws, size_t ws_size,
                              hipStream_t stream) {
  const float* x = (const float*)d_in[0];
  const float* node_mask = (const float*)d_in[1];
  const float* embed = (const float*)d_in[2];

  float* out = (float*)d_out;
  float* quant = out;
  float* out_idx = out + (size_t)ROWS * DIM;
  float* out_ppl = out_idx + ROWS;

  unsigned long long* best = (unsigned long long*)((char*)d_ws + WS_BEST);
  float* counts = (float*)((char*)d_ws + WS_COUNTS);
  unsigned* emax2 = (unsigned*)((char*)d_ws + WS_EMAX);
  float* enh = (float*)((char*)d_ws + WS_ENH);
  short* eswz = (short*)((char*)d_ws + WS_ESWZ);

  hipMemsetAsync(d_ws, 0, WS_ENH, stream);  // best + counts + emax2
  vq_enorm<<<NCODES / 256, 256, 0, stream>>>(embed, enh, emax2);
  if (ws_size >= WS_NEED) {
    vq_prep_e<<<256, 256, 0, stream>>>(embed, eswz);
    vq_screen<<<dim3(ROWS / 128, NCODES / (CTS_PER_BLOCK * 16)), 256, 0, stream>>>(
        x, embed, eswz, enh, (const float*)emax2, best);
  } else {
    vq_score_fb<<<dim3(ROWS / 256, NCODES / KT_FB), 256, 0, stream>>>(x, embed, enh, best);
  }
  vq_finalize<<<ROWS * DIM / 256, 256, 0, stream>>>(best, embed, node_mask, quant, out_idx, counts);
  vq_perplexity<<<1, 256, 0, stream>>>(counts, out_ppl);
}